// Round 15
// baseline (28.476 us; speedup 1.0000x reference)
//
#include <hip/hip_runtime.h>

// (B, S, H) = (8, 2048, 1024), fp32.
// Degenerate math: scores == 1/S exactly (softmax of a constant vector);
// context[b,h] == mean_s enc[b,s,h]; decoder_state cancels entirely.
// Lessons: R2 — grid.sync() ~200us; R3 — contended atomics; R7/R8 —
//   single-dispatch coherence 10x worse; R10 — 512 deep blocks best;
//   R11 — 1 blk/CU regressed; R13 — nt loads: 16.16us (best).
// R14: combine-free single dispatch — block owns (batch, 16-col slice),
//   reads all 2048 rows for its columns (strided 64 B/row), LDS tree,
//   writes its 16 outputs directly. No partials, no 2nd kernel, no
//   coherence. Tests whether HBM absorbs 64B-granular 4KB-strided reads.
#define BB 8
#define SS 2048
#define HH 1024
#define NSLICE 64              // 16-col slices per batch
#define NBLK (BB * NSLICE)     // 512 blocks
#define SCORES_PER_BLK ((BB * SS) / NBLK)  // 32

typedef float vf4 __attribute__((ext_vector_type(4)));

__global__ void __launch_bounds__(256, 4)
att_colown_kernel(const float* __restrict__ enc, float* __restrict__ out) {
    const int g = blockIdx.x;
    const int b = g >> 6;              // / NSLICE
    const int slice = g & (NSLICE - 1);
    const int t = threadIdx.x;
    const int c4 = t & 3;              // float4 within the 16-col slice
    const int rg = t >> 2;             // row group 0..63

    const vf4* p = (const vf4*)(enc + (size_t)b * SS * HH + slice * 16) + c4;

    vf4 acc = (vf4)(0.f);
    #pragma unroll
    for (int pass = 0; pass < 4; ++pass) {
        vf4 v[8];
        #pragma unroll
        for (int s = 0; s < 8; ++s) {
            int r = rg + (pass * 8 + s) * 64;
            v[s] = __builtin_nontemporal_load(p + (size_t)r * (HH / 4));
        }
        #pragma unroll
        for (int st = 4; st > 0; st >>= 1) {
            #pragma unroll
            for (int s = 0; s < st; ++s) v[s] += v[s + st];
        }
        acc += v[0];
    }

    // scores: 32 per block, independent of the reduction
    const float inv = 1.0f / SS;
    if (t >= 192 && t < 192 + SCORES_PER_BLK) {
        out[BB * HH + g * SCORES_PER_BLK + (t - 192)] = inv;
    }

    // LDS tree over row groups (layout t = rg*4 + c4; strides multiple of 4
    // preserve c4). 256 vf4 = 4 KB.
    __shared__ vf4 buf[256];
    buf[t] = acc;
    __syncthreads();
    #pragma unroll
    for (int s = 128; s >= 4; s >>= 1) {
        if (t < s) buf[t] += buf[t + s];
        __syncthreads();
    }
    if (t < 4) {
        vf4 r = buf[t] * inv;
        *((vf4*)(out + (size_t)b * HH + slice * 16) + t) = r;
    }
}

// Fallback (never expected): direct full-column sums, no workspace needed.
__global__ void __launch_bounds__(256)
att_direct_kernel(const float* __restrict__ enc, float* __restrict__ out) {
    int tid = blockIdx.x * blockDim.x + threadIdx.x;
    if (tid < BB * HH) {
        int b = tid >> 10;
        int h = tid & (HH - 1);
        const float* p = enc + (size_t)b * SS * HH + h;
        float acc = 0.f;
        for (int s = 0; s < SS; ++s) acc += p[(size_t)s * HH];
        out[tid] = acc * (1.0f / SS);
    } else if (tid < BB * HH + BB * SS) {
        out[tid] = 1.0f / SS;
    }
}

extern "C" void kernel_launch(void* const* d_in, const int* in_sizes, int n_in,
                              void* d_out, int out_size, void* d_ws, size_t ws_size,
                              hipStream_t stream) {
    const float* enc = (const float*)d_in[1];  // encoder_outputs (B,S,H)
    float* out = (float*)d_out;                // [context (B*H) | scores (B*S)]
    (void)d_ws; (void)ws_size;
    att_colown_kernel<<<NBLK, 256, 0, stream>>>(enc, out);
}

// Round 16
// 16.174 us; speedup vs baseline: 1.7606x; 1.7606x over previous
//
#include <hip/hip_runtime.h>

// (B, S, H) = (8, 2048, 1024), fp32.
// Degenerate math: scores == 1/S exactly (softmax of a constant vector);
// context[b,h] == mean_s enc[b,s,h]; decoder_state cancels entirely.
// FINAL (R13 config, 16.16us measured): 2-dispatch partial/finalize.
// Ladder: 32.4 (R1 naive-ish) -> 23.7 (16-deep MLP) -> 19.5 (wide finalize)
//   -> 17.4 (512 deep blocks, 2 MiB partials) -> 16.16 (nontemporal loads).
// Dead ends, each with mechanism: grid.sync ~200us (R2); contended atomics
//   (R3/R7); release-flag coherence = per-block L2 flush ~200us (R8);
//   1 blk/CU under-subscription (R11); 64B-granular strided single-pass
//   reads ~2.7 TB/s (R14). Roofline: 64 MiB @ 6.8 TB/s + partial round-trip
//   + finalize + 2 graph nodes ~= 15.4us composite; 16.16 is within ~5%.
#define BB 8
#define SS 2048
#define HH 1024
#define NCHUNK 64            // S-chunks per batch
#define CHUNK (SS / NCHUNK)  // 32 rows per block
#define NBLK (BB * NCHUNK)   // 512 blocks

typedef float vf4 __attribute__((ext_vector_type(4)));

// Kernel A: block g=(b,c) sums its 32-row chunk; thread t owns float4 column
// h=4t..4t+3. 4 passes x 8 independent nontemporal loads, fully unrolled.
__global__ void __launch_bounds__(256, 4)
att_partial_kernel(const float* __restrict__ enc, float* __restrict__ partial) {
    const int g = blockIdx.x;
    const int b = g >> 6;            // / NCHUNK
    const int c = g & (NCHUNK - 1);
    const int t = threadIdx.x;
    const vf4* p =
        (const vf4*)(enc + ((size_t)b * SS + (size_t)c * CHUNK) * HH) + t;

    vf4 acc = (vf4)(0.f);
    #pragma unroll
    for (int pass = 0; pass < 4; ++pass) {
        vf4 v[8];
        #pragma unroll
        for (int s = 0; s < 8; ++s)
            v[s] = __builtin_nontemporal_load(p + (size_t)(pass * 8 + s) * (HH / 4));
        #pragma unroll
        for (int st = 4; st > 0; st >>= 1) {
            #pragma unroll
            for (int s = 0; s < st; ++s) v[s] += v[s + st];
        }
        acc += v[0];
    }
    *((vf4*)(partial + (size_t)g * HH) + t) = acc;  // g == b*NCHUNK + c
}

// Kernel B: 128 blocks x 256 threads. Block = (b, 64-wide h slice); wave cq
// sums chunks c = cq*16..cq*16+15 (coalesced 256 B/wave reads), LDS[4][64]
// cross-wave combine; fills 128 scores per block.
__global__ void __launch_bounds__(256)
att_finalize_kernel(const float* __restrict__ partial, float* __restrict__ out) {
    const int blk = blockIdx.x;        // 0..127
    const int b = blk >> 4;            // / 16
    const int hbase = (blk & 15) * 64;
    const int t = threadIdx.x;
    const int hl = t & 63;
    const int cq = t >> 6;             // 0..3

    const float* p =
        partial + ((size_t)(b * NCHUNK + cq * 16)) * HH + hbase + hl;
    float acc = 0.f;
    #pragma unroll
    for (int c = 0; c < 16; ++c) acc += p[(size_t)c * HH];

    const float inv = 1.0f / SS;
    if (t >= 64 && t < 192) {
        out[BB * HH + blk * 128 + (t - 64)] = inv;
    }

    __shared__ float lds[4][64];
    lds[cq][hl] = acc;
    __syncthreads();
    if (t < 64) {
        float s = lds[0][t] + lds[1][t] + lds[2][t] + lds[3][t];
        out[b * HH + hbase + t] = s * inv;
    }
}

// Fallback (workspace too small): direct full-column sums.
__global__ void __launch_bounds__(256)
att_direct_kernel(const float* __restrict__ enc, float* __restrict__ out) {
    int tid = blockIdx.x * blockDim.x + threadIdx.x;
    if (tid < BB * HH) {
        int b = tid >> 10;
        int h = tid & (HH - 1);
        const float* p = enc + (size_t)b * SS * HH + h;
        float acc = 0.f;
        for (int s = 0; s < SS; ++s) acc += p[(size_t)s * HH];
        out[tid] = acc * (1.0f / SS);
    } else if (tid < BB * HH + BB * SS) {
        out[tid] = 1.0f / SS;
    }
}

extern "C" void kernel_launch(void* const* d_in, const int* in_sizes, int n_in,
                              void* d_out, int out_size, void* d_ws, size_t ws_size,
                              hipStream_t stream) {
    const float* enc = (const float*)d_in[1];  // encoder_outputs (B,S,H)
    float* out = (float*)d_out;                // [context (B*H) | scores (B*S)]

    const size_t part_bytes = (size_t)NBLK * HH * sizeof(float);  // 2 MiB
    if (d_ws != nullptr && ws_size >= part_bytes) {
        float* partial = (float*)d_ws;
        att_partial_kernel<<<NBLK, 256, 0, stream>>>(enc, partial);
        att_finalize_kernel<<<128, 256, 0, stream>>>(partial, out);
    } else {
        const int total_out = BB * HH + BB * SS;
        att_direct_kernel<<<(total_out + 255) / 256, 256, 0, stream>>>(enc, out);
    }
}